// Round 11
// baseline (311.052 us; speedup 1.0000x reference)
//
#include <hip/hip_runtime.h>

#define F_IN 256
#define CHUNK 8192
#define CAP 10240   // per-bucket LDS edge capacity (mean 8184 + pad 768 + 4sig)

typedef short bf8_t __attribute__((ext_vector_type(8)));   // 8 bf16
typedef float f4_t  __attribute__((ext_vector_type(4)));   // 4 fp32 acc

__device__ __forceinline__ unsigned short f2bf(float f) {
  unsigned u = __float_as_uint(f);
  unsigned r = (u + 0x7FFFu + ((u >> 16) & 1u)) >> 16;  // RNE
  return (unsigned short)r;
}
#define BF_LO(d) __uint_as_float((d) << 16)
#define BF_HI(d) __uint_as_float((d) & 0xFFFF0000u)

__device__ __forceinline__ bf8_t pack8(float4 a, float4 b) {
  bf8_t r;
  r[0] = (short)f2bf(a.x); r[1] = (short)f2bf(a.y);
  r[2] = (short)f2bf(a.z); r[3] = (short)f2bf(a.w);
  r[4] = (short)f2bf(b.x); r[5] = (short)f2bf(b.y);
  r[6] = (short)f2bf(b.z); r[7] = (short)f2bf(b.w);
  return r;
}

// ------- W prep: WbT[n][k] = bf16(W[k][n]); zero row N of hb -----------------
__global__ __launch_bounds__(256) void wprep_kernel(
    const float* __restrict__ W, unsigned short* __restrict__ WbT,
    unsigned short* __restrict__ hb, int N) {
  const int t = threadIdx.x;
  const int i = blockIdx.x * 256 + t;  // 0..16383
  const int k = i >> 6, n = i & 63;
  WbT[n * 256 + k] = f2bf(W[i]);
  if (blockIdx.x == 0 && t < 64) hb[(size_t)N * 64 + t] = 0;  // zero row
}

// ------- direct GEMM: hb = bf16(rsqrt(deg+1)*(x @ W)); B in LDS --------------
__global__ __launch_bounds__(256) void gemm_direct_kernel(
    const float* __restrict__ x, const unsigned short* __restrict__ WbT,
    const int* __restrict__ deg, unsigned short* __restrict__ hb, int M) {
  __shared__ short Bs[64][264];   // [n][k], stride 264 (528 B) -> 2-way banks
  const int t = threadIdx.x;
  for (int i = t; i < 2048; i += 256) {
    const int n = i >> 5, kq = (i & 31) << 3;
    *(uint4*)&Bs[n][kq] = *(const uint4*)(WbT + n * 256 + kq);
  }
  __syncthreads();

  const int brow = blockIdx.x * 128;
  const int w = t >> 6;
  const int l = t & 63;
  const int ml = l & 15;
  const int quad = l >> 4;

  const int r0 = min(brow + w * 32 + ml, M - 1);
  const int r1 = min(brow + w * 32 + 16 + ml, M - 1);
  const float* xr0 = x + (size_t)r0 * F_IN + (quad << 3);
  const float* xr1 = x + (size_t)r1 * F_IN + (quad << 3);

  f4_t acc[2][4];
#pragma unroll
  for (int a = 0; a < 2; ++a)
#pragma unroll
    for (int b = 0; b < 4; ++b) acc[a][b] = (f4_t){0.f, 0.f, 0.f, 0.f};

#pragma unroll
  for (int k0 = 0; k0 < F_IN; k0 += 32) {
    bf8_t afr[2];
    {
      const float4 a0 = *(const float4*)(xr0 + k0);
      const float4 a1 = *(const float4*)(xr0 + k0 + 4);
      afr[0] = pack8(a0, a1);
      const float4 c0 = *(const float4*)(xr1 + k0);
      const float4 c1 = *(const float4*)(xr1 + k0 + 4);
      afr[1] = pack8(c0, c1);
    }
    bf8_t bfr[4];
#pragma unroll
    for (int nt = 0; nt < 4; ++nt)
      bfr[nt] = *(const bf8_t*)&Bs[nt * 16 + ml][k0 + (quad << 3)];
#pragma unroll
    for (int mt = 0; mt < 2; ++mt)
#pragma unroll
      for (int nt = 0; nt < 4; ++nt)
        acc[mt][nt] = __builtin_amdgcn_mfma_f32_16x16x32_bf16(
            afr[mt], bfr[nt], acc[mt][nt], 0, 0, 0);
  }

#pragma unroll
  for (int mt = 0; mt < 2; ++mt) {
#pragma unroll
    for (int reg = 0; reg < 4; ++reg) {
      const int row = brow + w * 32 + mt * 16 + (quad << 2) + reg;
      if (row < M) {
        const float di = rsqrtf((float)deg[row] + 1.f);
#pragma unroll
        for (int nt = 0; nt < 4; ++nt)
          hb[(size_t)row * 64 + nt * 16 + ml] = f2bf(di * acc[mt][nt][reg]);
      }
    }
  }
}

// ------- block-local sort: each chunk sorted by 256-node bucket --------------
__global__ __launch_bounds__(512) void sort_local_kernel(
    const int* __restrict__ src_arr, const int* __restrict__ dst_arr,
    int* __restrict__ espB, int* __restrict__ segStart, int* __restrict__ segCnt,
    int E, int NBK) {
  __shared__ int hist[512];
  __shared__ int s[512];
  __shared__ int cur[512];
  const int t = threadIdx.x;
  const int blk = blockIdx.x;
  const int base = blk * CHUNK;
  const int cnt = min(CHUNK, E - base);
  for (int i = t; i < NBK; i += 512) hist[i] = 0;
  __syncthreads();
  int pk[16], bk[16];
#pragma unroll
  for (int k = 0; k < 16; ++k) {
    const int i = t + k * 512;
    bk[k] = -1;
    if (i < cnt) {
      const int sv = src_arr[base + i];
      const int dv = dst_arr[base + i];
      pk[k] = sv | ((dv & 255) << 24);
      bk[k] = dv >> 8;
      atomicAdd(&hist[bk[k]], 1);
    }
  }
  __syncthreads();
  const int v = (t < NBK) ? hist[t] : 0;
  s[t] = v;
  __syncthreads();
#pragma unroll
  for (int off = 1; off < 512; off <<= 1) {
    int add = (t >= off) ? s[t - off] : 0;
    __syncthreads();
    s[t] += add;
    __syncthreads();
  }
  if (t < NBK) {
    const int excl = s[t] - v;
    cur[t] = excl;
    segStart[blk * NBK + t] = base + excl;   // block-major: dense writes
    segCnt[blk * NBK + t] = v;
  }
  __syncthreads();
#pragma unroll
  for (int k = 0; k < 16; ++k) {
    if (bk[k] >= 0) {
      const int pos = atomicAdd(&cur[bk[k]], 1);
      espB[base + pos] = pk[k];              // dense 32 KB streaming write
    }
  }
}

// ------- per-bucket degree histogram (LDS atomics, plain global stores) ------
__global__ __launch_bounds__(512) void deg_hist_kernel(
    const int* __restrict__ espB, const int* __restrict__ segStart,
    const int* __restrict__ segCnt, int* __restrict__ deg,
    int N, int NBK, int NCH) {
  __shared__ int segS[512];
  __shared__ int segC[512];
  __shared__ int hist[256];
  const int t = threadIdx.x;
  const int b = blockIdx.x;
  segS[t] = 0;
  segC[t] = 0;
  if (t < 256) hist[t] = 0;
  __syncthreads();
  for (int i = t; i < NCH; i += 512) {
    segS[i] = segStart[i * NBK + b];
    segC[i] = segCnt[i * NBK + b];
  }
  __syncthreads();
  const int sw = t >> 4, sl = t & 15;
  for (int seg = sw; seg < NCH; seg += 32) {
    const int sS = segS[seg], c = segC[seg];
    for (int j = sl; j < c; j += 16)
      atomicAdd(&hist[((unsigned)__builtin_nontemporal_load(espB + sS + j)) >> 24], 1);
  }
  __syncthreads();
  if (t < 256) {
    const int node = b * 256 + t;
    if (node < N) deg[node] = hist[t];
  }
}

// ------- merged bin + aggregate: serial-walk, zero-shuffle gather ------------
// R9 structure (best measured: 300.6 us total, bin_agg 61.4 us at the 2.7 TB/s
// L2-miss fill floor verified across 8 designs). 8 nodes/wave x 8
// feature-lanes/node; each lane walks its node's LDS edge list depth-4.
// Segments padded to x4 with zero-row index N -> no masks/clamps. No shuffle
// reduction; all 64 lanes store. espB index stream is non-temporal (zero
// reuse; keeps hb lines in L2 for the gather).
__global__ __launch_bounds__(512) void bin_agg_kernel(
    const int* __restrict__ espB, const int* __restrict__ segStart,
    const int* __restrict__ segCnt, const int* __restrict__ deg,
    const unsigned short* __restrict__ hb, const float* __restrict__ bg,
    unsigned short* __restrict__ g, int N, int NBK, int NCH) {
  __shared__ int eLDS[CAP];      // 40 KB edge list (padded segments)
  __shared__ int segS[512];
  __shared__ int segC[512];
  __shared__ int sbuf[256];
  __shared__ int hist[256];      // true per-node count
  __shared__ int cur[256];
  __shared__ int stt[256];       // padded segment start
  const int t = threadIdx.x;
  const int b = blockIdx.x;
  segS[t] = 0;
  segC[t] = 0;
  __syncthreads();
  for (int i = t; i < NCH; i += 512) {
    segS[i] = segStart[i * NBK + b];
    segC[i] = segCnt[i * NBK + b];
  }
  // per-node counts from deg; scan PADDED counts (x4) for segment offsets
  int v2 = 0, vp = 0;
  if (t < 256) {
    const int node = b * 256 + t;
    v2 = (node < N) ? deg[node] : 0;
    vp = (v2 + 3) & ~3;
    sbuf[t] = vp;
  }
  __syncthreads();
#pragma unroll
  for (int off = 1; off < 256; off <<= 1) {
    int add = 0;
    if (t < 256 && t >= off) add = sbuf[t - off];
    __syncthreads();
    if (t < 256) sbuf[t] += add;
    __syncthreads();
  }
  if (t < 256) {
    const int excl = sbuf[t] - vp;
    cur[t] = excl;
    stt[t] = excl;
    hist[t] = v2;
  }
  __syncthreads();

  const int sw = t >> 4;      // 32 subwaves of 16 lanes
  const int sl = t & 15;

  // scatter into LDS edge list (non-temporal espB stream)
  for (int seg = sw; seg < NCH; seg += 32) {
    const int sS = segS[seg], c = segC[seg];
    for (int j = sl; j < c; j += 16) {
      const int p = __builtin_nontemporal_load(espB + sS + j);
      const int pos = atomicAdd(&cur[((unsigned)p) >> 24], 1);
      if (pos < CAP) eLDS[pos] = p & 0x00FFFFFF;
    }
  }
  __syncthreads();
  // pad each segment to x4 with the zero-row index (cur[t] == stt+cn now)
  if (t < 256) {
    const int e0 = cur[t];
    const int e1 = stt[t] + ((hist[t] + 3) & ~3);
    for (int i2 = e0; i2 < e1 && i2 < CAP; ++i2) eLDS[i2] = N;
  }
  __syncthreads();

  // serial-walk gather: 8 waves x (8 nodes x 8 feature-lanes), 4 passes
  const int w = t >> 6;
  const int lane = t & 63;
  const int gi = lane >> 3;          // node sub-index within wave (0..7)
  const int fq = (lane & 7) << 3;    // feature octet (0,8,..,56)

#pragma unroll
  for (int p = 0; p < 4; ++p) {
    const int ln = p * 64 + w * 8 + gi;    // local node 0..255
    const int node = b * 256 + ln;
    const int cn = hist[ln];
    const int start = stt[ln];
    const int R = (cn + 3) >> 2;

    float acc[8] = {0.f, 0.f, 0.f, 0.f, 0.f, 0.f, 0.f, 0.f};
    int i = start;
    int s0 = 0, s1 = 0, s2 = 0, s3 = 0;
    if (R > 0) { s0 = eLDS[i]; s1 = eLDS[i + 1]; s2 = eLDS[i + 2]; s3 = eLDS[i + 3]; }
    for (int r = 0; r < R; ++r) {
      const uint4 r0 = *(const uint4*)(hb + (size_t)s0 * 64 + fq);
      const uint4 r1 = *(const uint4*)(hb + (size_t)s1 * 64 + fq);
      const uint4 r2 = *(const uint4*)(hb + (size_t)s2 * 64 + fq);
      const uint4 r3 = *(const uint4*)(hb + (size_t)s3 * 64 + fq);
      i += 4;
      if (r + 1 < R) { s0 = eLDS[i]; s1 = eLDS[i + 1]; s2 = eLDS[i + 2]; s3 = eLDS[i + 3]; }
      acc[0] += (BF_LO(r0.x) + BF_LO(r1.x)) + (BF_LO(r2.x) + BF_LO(r3.x));
      acc[1] += (BF_HI(r0.x) + BF_HI(r1.x)) + (BF_HI(r2.x) + BF_HI(r3.x));
      acc[2] += (BF_LO(r0.y) + BF_LO(r1.y)) + (BF_LO(r2.y) + BF_LO(r3.y));
      acc[3] += (BF_HI(r0.y) + BF_HI(r1.y)) + (BF_HI(r2.y) + BF_HI(r3.y));
      acc[4] += (BF_LO(r0.z) + BF_LO(r1.z)) + (BF_LO(r2.z) + BF_LO(r3.z));
      acc[5] += (BF_HI(r0.z) + BF_HI(r1.z)) + (BF_HI(r2.z) + BF_HI(r3.z));
      acc[6] += (BF_LO(r0.w) + BF_LO(r1.w)) + (BF_LO(r2.w) + BF_LO(r3.w));
      acc[7] += (BF_HI(r0.w) + BF_HI(r1.w)) + (BF_HI(r2.w) + BF_HI(r3.w));
    }

    if (node < N) {
      const float di = rsqrtf((float)(cn + 1));
      const uint4 rr = *(const uint4*)(hb + (size_t)node * 64 + fq);  // self
      const float4 bq0 = *(const float4*)(bg + fq);
      const float4 bq1 = *(const float4*)(bg + fq + 4);
      float4 v0 = make_float4(
          fmaxf(di * (acc[0] + BF_LO(rr.x)) + bq0.x, 0.f),
          fmaxf(di * (acc[1] + BF_HI(rr.x)) + bq0.y, 0.f),
          fmaxf(di * (acc[2] + BF_LO(rr.y)) + bq0.z, 0.f),
          fmaxf(di * (acc[3] + BF_HI(rr.y)) + bq0.w, 0.f));
      float4 v1 = make_float4(
          fmaxf(di * (acc[4] + BF_LO(rr.z)) + bq1.x, 0.f),
          fmaxf(di * (acc[5] + BF_HI(rr.z)) + bq1.y, 0.f),
          fmaxf(di * (acc[6] + BF_LO(rr.w)) + bq1.z, 0.f),
          fmaxf(di * (acc[7] + BF_HI(rr.w)) + bq1.w, 0.f));
      *(bf8_t*)(g + (size_t)node * 64 + fq) = pack8(v0, v1);
    }
  }
}

// ---------------- MFMA MLP: 256 nodes/block, 3 layers in LDS -----------------
__global__ __launch_bounds__(256) void mlp_mfma_kernel(
    const unsigned short* __restrict__ g,
    const float* __restrict__ W1, const float* __restrict__ b1,
    const float* __restrict__ W2, const float* __restrict__ b2,
    const float* __restrict__ W3, const float* __restrict__ b3,
    float* __restrict__ out, int N) {
  __shared__ short g64[256 * 72];   // [node][feat] bf16, stride 72 (h1 aliases)
  __shared__ short h2s[256 * 40];   // [node][feat] bf16, cols 16..31 zero
  __shared__ short W1s[32 * 72];    // [n][k] k<64
  __shared__ short W2s[16 * 40];    // [n][k] k<32
  __shared__ short W3s[16 * 40];    // [n][k] k<16, rest zero
  __shared__ float b1s[32], b2s[16], b3s[16];
  short* h1s = g64;                 // [node][feat] stride 40, alias after layer1

  const int t = threadIdx.x;
  const int node0 = blockIdx.x * 256;
  for (int i = t; i < 256 * 40; i += 256) h2s[i] = 0;
  for (int i = t; i < 16 * 40; i += 256) W3s[i] = 0;
  if (t < 32) b1s[t] = b1[t];
  if (t < 16) { b2s[t] = b2[t]; b3s[t] = (t < 10) ? b3[t] : 0.f; }
  __syncthreads();
  for (int i = t; i < 2048; i += 256) { const int k = i >> 5, n = i & 31; W1s[n * 72 + k] = (short)f2bf(W1[i]); }
  for (int i = t; i < 512;  i += 256) { const int k = i >> 4, n = i & 15; W2s[n * 40 + k] = (short)f2bf(W2[i]); }
  if (t < 160) { const int k = t / 10, n = t % 10; W3s[n * 40 + k] = (short)f2bf(W3[t]); }
  // stage g: 8 lanes per row -> 1 KB contiguous per wave-instruction
  for (int i = t; i < 2048; i += 256) {
    const int row = i >> 3, q = (i & 7) << 3;
    const int nd = min(node0 + row, N - 1);
    *(uint4*)&g64[row * 72 + q] = *(const uint4*)(g + (size_t)nd * 64 + q);
  }
  __syncthreads();

  const int w = t >> 6;
  const int lane = t & 63;
  const int ml = lane & 15;
  const int quad = lane >> 4;

  // layer 1: (256x64) @ (64x32)
  bf8_t a1f[4][2], b1f[2][2];
#pragma unroll
  for (int mt = 0; mt < 4; ++mt)
#pragma unroll
    for (int ks = 0; ks < 2; ++ks)
      a1f[mt][ks] = *(const bf8_t*)&g64[(w * 64 + mt * 16 + ml) * 72 + ks * 32 + quad * 8];
#pragma unroll
  for (int nt = 0; nt < 2; ++nt)
#pragma unroll
    for (int ks = 0; ks < 2; ++ks)
      b1f[nt][ks] = *(const bf8_t*)&W1s[(nt * 16 + ml) * 72 + ks * 32 + quad * 8];
  f4_t acc1[4][2];
#pragma unroll
  for (int mt = 0; mt < 4; ++mt)
#pragma unroll
    for (int nt = 0; nt < 2; ++nt) acc1[mt][nt] = (f4_t){0.f, 0.f, 0.f, 0.f};
#pragma unroll
  for (int ks = 0; ks < 2; ++ks)
#pragma unroll
    for (int mt = 0; mt < 4; ++mt)
#pragma unroll
      for (int nt = 0; nt < 2; ++nt)
        acc1[mt][nt] = __builtin_amdgcn_mfma_f32_16x16x32_bf16(
            a1f[mt][ks], b1f[nt][ks], acc1[mt][nt], 0, 0, 0);
  __syncthreads();
#pragma unroll
  for (int mt = 0; mt < 4; ++mt)
#pragma unroll
    for (int nt = 0; nt < 2; ++nt)
#pragma unroll
      for (int reg = 0; reg < 4; ++reg) {
        const int row = w * 64 + mt * 16 + quad * 4 + reg;
        const int col = nt * 16 + ml;
        h1s[row * 40 + col] = (short)f2bf(fmaxf(acc1[mt][nt][reg] + b1s[col], 0.f));
      }
  __syncthreads();

  // layer 2: (256x32) @ (32x16)
  bf8_t a2f[4];
#pragma unroll
  for (int mt = 0; mt < 4; ++mt)
    a2f[mt] = *(const bf8_t*)&h1s[(w * 64 + mt * 16 + ml) * 40 + quad * 8];
  const bf8_t b2f = *(const bf8_t*)&W2s[ml * 40 + quad * 8];
  f4_t acc2[4];
#pragma unroll
  for (int mt = 0; mt < 4; ++mt) {
    acc2[mt] = (f4_t){0.f, 0.f, 0.f, 0.f};
    acc2[mt] = __builtin_amdgcn_mfma_f32_16x16x32_bf16(a2f[mt], b2f, acc2[mt], 0, 0, 0);
  }
  __syncthreads();
#pragma unroll
  for (int mt = 0; mt < 4; ++mt)
#pragma unroll
    for (int reg = 0; reg < 4; ++reg) {
      const int row = w * 64 + mt * 16 + quad * 4 + reg;
      h2s[row * 40 + ml] = (short)f2bf(fmaxf(acc2[mt][reg] + b2s[ml], 0.f));
    }
  __syncthreads();

  // layer 3: (256x16) @ (16x10), K zero-padded to 32
  bf8_t a3f[4];
#pragma unroll
  for (int mt = 0; mt < 4; ++mt)
    a3f[mt] = *(const bf8_t*)&h2s[(w * 64 + mt * 16 + ml) * 40 + quad * 8];
  const bf8_t b3f = *(const bf8_t*)&W3s[ml * 40 + quad * 8];
#pragma unroll
  for (int mt = 0; mt < 4; ++mt) {
    f4_t acc3 = (f4_t){0.f, 0.f, 0.f, 0.f};
    acc3 = __builtin_amdgcn_mfma_f32_16x16x32_bf16(a3f[mt], b3f, acc3, 0, 0, 0);
#pragma unroll
    for (int reg = 0; reg < 4; ++reg) {
      const int node = node0 + w * 64 + mt * 16 + quad * 4 + reg;
      if (ml < 10 && node < N) out[(size_t)node * 10 + ml] = acc3[reg] + b3s[ml];
    }
  }
}

extern "C" void kernel_launch(void* const* d_in, const int* in_sizes, int n_in,
                              void* d_out, int out_size, void* d_ws, size_t ws_size,
                              hipStream_t stream) {
  const float* x     = (const float*)d_in[0];
  const int*   ei    = (const int*)d_in[1];
  const float* W_gcn = (const float*)d_in[2];
  const float* b_gcn = (const float*)d_in[3];
  const float* W1    = (const float*)d_in[4];
  const float* b1    = (const float*)d_in[5];
  const float* W2    = (const float*)d_in[6];
  const float* b2    = (const float*)d_in[7];
  const float* W3    = (const float*)d_in[8];
  const float* b3    = (const float*)d_in[9];
  float* out = (float*)d_out;

  const int N = in_sizes[0] / F_IN;   // 100000
  const int E = in_sizes[1] / 2;      // 3200000
  const int* src = ei;
  const int* dst = ei + E;
  const int NBK = (N + 255) >> 8;     // 391 buckets of 256 nodes
  const int NCH = (E + CHUNK - 1) / CHUNK;  // 391 chunks

  unsigned short* hb = (unsigned short*)d_ws;            // (N+1)*64 us (+zero row)
  int*   deg         = (int*)(hb + (size_t)(N + 1) * 64);// N i      (0.4 MB)
  int*   espB        = deg + N;                          // E i      (12.8 MB)
  int*   segStart    = espB + E;                         // NCH*NBK i (0.61 MB)
  int*   segCnt      = segStart + NCH * NBK;             // NCH*NBK i (0.61 MB)
  unsigned short* WbT= (unsigned short*)(segCnt + NCH * NBK); // 16384 us (32 KB)
  unsigned short* g  = WbT + 16384;                      // N*64 us  (12.8 MB)

  wprep_kernel<<<64, 256, 0, stream>>>(W_gcn, WbT, hb, N);
  sort_local_kernel<<<NCH, 512, 0, stream>>>(
      src, dst, espB, segStart, segCnt, E, NBK);
  deg_hist_kernel<<<NBK, 512, 0, stream>>>(
      espB, segStart, segCnt, deg, N, NBK, NCH);

  gemm_direct_kernel<<<(N + 127) / 128, 256, 0, stream>>>(x, WbT, deg, hb, N);

  bin_agg_kernel<<<NBK, 512, 0, stream>>>(
      espB, segStart, segCnt, deg, hb, b_gcn, g, N, NBK, NCH);

  mlp_mfma_kernel<<<(N + 255) / 256, 256, 0, stream>>>(
      g, W1, b1, W2, b2, W3, b3, out, N);
}

// Round 12
// 300.002 us; speedup vs baseline: 1.0368x; 1.0368x over previous
//
#include <hip/hip_runtime.h>

#define F_IN 256
#define CHUNK 8192
#define CAP 10240   // per-bucket LDS edge capacity (mean 8184 + pad 768 + 4sig)

typedef short bf8_t __attribute__((ext_vector_type(8)));   // 8 bf16
typedef float f4_t  __attribute__((ext_vector_type(4)));   // 4 fp32 acc

__device__ __forceinline__ unsigned short f2bf(float f) {
  unsigned u = __float_as_uint(f);
  unsigned r = (u + 0x7FFFu + ((u >> 16) & 1u)) >> 16;  // RNE
  return (unsigned short)r;
}
#define BF_LO(d) __uint_as_float((d) << 16)
#define BF_HI(d) __uint_as_float((d) & 0xFFFF0000u)

__device__ __forceinline__ bf8_t pack8(float4 a, float4 b) {
  bf8_t r;
  r[0] = (short)f2bf(a.x); r[1] = (short)f2bf(a.y);
  r[2] = (short)f2bf(a.z); r[3] = (short)f2bf(a.w);
  r[4] = (short)f2bf(b.x); r[5] = (short)f2bf(b.y);
  r[6] = (short)f2bf(b.z); r[7] = (short)f2bf(b.w);
  return r;
}

// ------- W prep: WbT[n][k] = bf16(W[k][n]); zero row N of hb -----------------
__global__ __launch_bounds__(256) void wprep_kernel(
    const float* __restrict__ W, unsigned short* __restrict__ WbT,
    unsigned short* __restrict__ hb, int N) {
  const int t = threadIdx.x;
  const int i = blockIdx.x * 256 + t;  // 0..16383
  const int k = i >> 6, n = i & 63;
  WbT[n * 256 + k] = f2bf(W[i]);
  if (blockIdx.x == 0 && t < 64) hb[(size_t)N * 64 + t] = 0;  // zero row
}

// ------- direct GEMM: hb = bf16(rsqrt(deg+1)*(x @ W)); B in LDS --------------
__global__ __launch_bounds__(256) void gemm_direct_kernel(
    const float* __restrict__ x, const unsigned short* __restrict__ WbT,
    const int* __restrict__ deg, unsigned short* __restrict__ hb, int M) {
  __shared__ short Bs[64][264];   // [n][k], stride 264 (528 B) -> 2-way banks
  const int t = threadIdx.x;
  for (int i = t; i < 2048; i += 256) {
    const int n = i >> 5, kq = (i & 31) << 3;
    *(uint4*)&Bs[n][kq] = *(const uint4*)(WbT + n * 256 + kq);
  }
  __syncthreads();

  const int brow = blockIdx.x * 128;
  const int w = t >> 6;
  const int l = t & 63;
  const int ml = l & 15;
  const int quad = l >> 4;

  const int r0 = min(brow + w * 32 + ml, M - 1);
  const int r1 = min(brow + w * 32 + 16 + ml, M - 1);
  const float* xr0 = x + (size_t)r0 * F_IN + (quad << 3);
  const float* xr1 = x + (size_t)r1 * F_IN + (quad << 3);

  f4_t acc[2][4];
#pragma unroll
  for (int a = 0; a < 2; ++a)
#pragma unroll
    for (int b = 0; b < 4; ++b) acc[a][b] = (f4_t){0.f, 0.f, 0.f, 0.f};

#pragma unroll
  for (int k0 = 0; k0 < F_IN; k0 += 32) {
    bf8_t afr[2];
    {
      const float4 a0 = *(const float4*)(xr0 + k0);
      const float4 a1 = *(const float4*)(xr0 + k0 + 4);
      afr[0] = pack8(a0, a1);
      const float4 c0 = *(const float4*)(xr1 + k0);
      const float4 c1 = *(const float4*)(xr1 + k0 + 4);
      afr[1] = pack8(c0, c1);
    }
    bf8_t bfr[4];
#pragma unroll
    for (int nt = 0; nt < 4; ++nt)
      bfr[nt] = *(const bf8_t*)&Bs[nt * 16 + ml][k0 + (quad << 3)];
#pragma unroll
    for (int mt = 0; mt < 2; ++mt)
#pragma unroll
      for (int nt = 0; nt < 4; ++nt)
        acc[mt][nt] = __builtin_amdgcn_mfma_f32_16x16x32_bf16(
            afr[mt], bfr[nt], acc[mt][nt], 0, 0, 0);
  }

#pragma unroll
  for (int mt = 0; mt < 2; ++mt) {
#pragma unroll
    for (int reg = 0; reg < 4; ++reg) {
      const int row = brow + w * 32 + mt * 16 + (quad << 2) + reg;
      if (row < M) {
        const float di = rsqrtf((float)deg[row] + 1.f);
#pragma unroll
        for (int nt = 0; nt < 4; ++nt)
          hb[(size_t)row * 64 + nt * 16 + ml] = f2bf(di * acc[mt][nt][reg]);
      }
    }
  }
}

// ------- block-local sort: each chunk sorted by 256-node bucket --------------
__global__ __launch_bounds__(512) void sort_local_kernel(
    const int* __restrict__ src_arr, const int* __restrict__ dst_arr,
    int* __restrict__ espB, int* __restrict__ segStart, int* __restrict__ segCnt,
    int E, int NBK) {
  __shared__ int hist[512];
  __shared__ int s[512];
  __shared__ int cur[512];
  const int t = threadIdx.x;
  const int blk = blockIdx.x;
  const int base = blk * CHUNK;
  const int cnt = min(CHUNK, E - base);
  for (int i = t; i < NBK; i += 512) hist[i] = 0;
  __syncthreads();
  int pk[16], bk[16];
#pragma unroll
  for (int k = 0; k < 16; ++k) {
    const int i = t + k * 512;
    bk[k] = -1;
    if (i < cnt) {
      const int sv = src_arr[base + i];
      const int dv = dst_arr[base + i];
      pk[k] = sv | ((dv & 255) << 24);
      bk[k] = dv >> 8;
      atomicAdd(&hist[bk[k]], 1);
    }
  }
  __syncthreads();
  const int v = (t < NBK) ? hist[t] : 0;
  s[t] = v;
  __syncthreads();
#pragma unroll
  for (int off = 1; off < 512; off <<= 1) {
    int add = (t >= off) ? s[t - off] : 0;
    __syncthreads();
    s[t] += add;
    __syncthreads();
  }
  if (t < NBK) {
    const int excl = s[t] - v;
    cur[t] = excl;
    segStart[blk * NBK + t] = base + excl;   // block-major: dense writes
    segCnt[blk * NBK + t] = v;
  }
  __syncthreads();
#pragma unroll
  for (int k = 0; k < 16; ++k) {
    if (bk[k] >= 0) {
      const int pos = atomicAdd(&cur[bk[k]], 1);
      espB[base + pos] = pk[k];              // dense 32 KB streaming write
    }
  }
}

// ------- per-bucket degree histogram (LDS atomics, plain global stores) ------
__global__ __launch_bounds__(512) void deg_hist_kernel(
    const int* __restrict__ espB, const int* __restrict__ segStart,
    const int* __restrict__ segCnt, int* __restrict__ deg,
    int N, int NBK, int NCH) {
  __shared__ int segS[512];
  __shared__ int segC[512];
  __shared__ int hist[256];
  const int t = threadIdx.x;
  const int b = blockIdx.x;
  segS[t] = 0;
  segC[t] = 0;
  if (t < 256) hist[t] = 0;
  __syncthreads();
  for (int i = t; i < NCH; i += 512) {
    segS[i] = segStart[i * NBK + b];
    segC[i] = segCnt[i * NBK + b];
  }
  __syncthreads();
  const int sw = t >> 4, sl = t & 15;
  for (int seg = sw; seg < NCH; seg += 32) {
    const int sS = segS[seg], c = segC[seg];
    for (int j = sl; j < c; j += 16)
      atomicAdd(&hist[((unsigned)espB[sS + j]) >> 24], 1);
  }
  __syncthreads();
  if (t < 256) {
    const int node = b * 256 + t;
    if (node < N) deg[node] = hist[t];
  }
}

// ------- merged bin + aggregate: serial-walk, zero-shuffle gather ------------
// R9 structure exactly (best measured: 300.6 us total, bin_agg 61.4 us at the
// 2.7 TB/s L2-miss fill floor verified across 8 designs). 8 nodes/wave x 8
// feature-lanes/node; each lane walks its node's LDS edge list depth-4.
// Segments padded to x4 with zero-row index N -> no masks/clamps. No shuffle
// reduction; all 64 lanes store. NO non-temporal hints: R11 measured the NT
// espB load at +8 us (defeats sector reuse on the index stream; hb eviction
// by espB was never a real cost - FETCH identical both ways).
__global__ __launch_bounds__(512) void bin_agg_kernel(
    const int* __restrict__ espB, const int* __restrict__ segStart,
    const int* __restrict__ segCnt, const int* __restrict__ deg,
    const unsigned short* __restrict__ hb, const float* __restrict__ bg,
    unsigned short* __restrict__ g, int N, int NBK, int NCH) {
  __shared__ int eLDS[CAP];      // 40 KB edge list (padded segments)
  __shared__ int segS[512];
  __shared__ int segC[512];
  __shared__ int sbuf[256];
  __shared__ int hist[256];      // true per-node count
  __shared__ int cur[256];
  __shared__ int stt[256];       // padded segment start
  const int t = threadIdx.x;
  const int b = blockIdx.x;
  segS[t] = 0;
  segC[t] = 0;
  __syncthreads();
  for (int i = t; i < NCH; i += 512) {
    segS[i] = segStart[i * NBK + b];
    segC[i] = segCnt[i * NBK + b];
  }
  // per-node counts from deg; scan PADDED counts (x4) for segment offsets
  int v2 = 0, vp = 0;
  if (t < 256) {
    const int node = b * 256 + t;
    v2 = (node < N) ? deg[node] : 0;
    vp = (v2 + 3) & ~3;
    sbuf[t] = vp;
  }
  __syncthreads();
#pragma unroll
  for (int off = 1; off < 256; off <<= 1) {
    int add = 0;
    if (t < 256 && t >= off) add = sbuf[t - off];
    __syncthreads();
    if (t < 256) sbuf[t] += add;
    __syncthreads();
  }
  if (t < 256) {
    const int excl = sbuf[t] - vp;
    cur[t] = excl;
    stt[t] = excl;
    hist[t] = v2;
  }
  __syncthreads();

  const int sw = t >> 4;      // 32 subwaves of 16 lanes
  const int sl = t & 15;

  // scatter into LDS edge list
  for (int seg = sw; seg < NCH; seg += 32) {
    const int sS = segS[seg], c = segC[seg];
    for (int j = sl; j < c; j += 16) {
      const int p = espB[sS + j];
      const int pos = atomicAdd(&cur[((unsigned)p) >> 24], 1);
      if (pos < CAP) eLDS[pos] = p & 0x00FFFFFF;
    }
  }
  __syncthreads();
  // pad each segment to x4 with the zero-row index (cur[t] == stt+cn now)
  if (t < 256) {
    const int e0 = cur[t];
    const int e1 = stt[t] + ((hist[t] + 3) & ~3);
    for (int i2 = e0; i2 < e1 && i2 < CAP; ++i2) eLDS[i2] = N;
  }
  __syncthreads();

  // serial-walk gather: 8 waves x (8 nodes x 8 feature-lanes), 4 passes
  const int w = t >> 6;
  const int lane = t & 63;
  const int gi = lane >> 3;          // node sub-index within wave (0..7)
  const int fq = (lane & 7) << 3;    // feature octet (0,8,..,56)

#pragma unroll
  for (int p = 0; p < 4; ++p) {
    const int ln = p * 64 + w * 8 + gi;    // local node 0..255
    const int node = b * 256 + ln;
    const int cn = hist[ln];
    const int start = stt[ln];
    const int R = (cn + 3) >> 2;

    float acc[8] = {0.f, 0.f, 0.f, 0.f, 0.f, 0.f, 0.f, 0.f};
    int i = start;
    int s0 = 0, s1 = 0, s2 = 0, s3 = 0;
    if (R > 0) { s0 = eLDS[i]; s1 = eLDS[i + 1]; s2 = eLDS[i + 2]; s3 = eLDS[i + 3]; }
    for (int r = 0; r < R; ++r) {
      const uint4 r0 = *(const uint4*)(hb + (size_t)s0 * 64 + fq);
      const uint4 r1 = *(const uint4*)(hb + (size_t)s1 * 64 + fq);
      const uint4 r2 = *(const uint4*)(hb + (size_t)s2 * 64 + fq);
      const uint4 r3 = *(const uint4*)(hb + (size_t)s3 * 64 + fq);
      i += 4;
      if (r + 1 < R) { s0 = eLDS[i]; s1 = eLDS[i + 1]; s2 = eLDS[i + 2]; s3 = eLDS[i + 3]; }
      acc[0] += (BF_LO(r0.x) + BF_LO(r1.x)) + (BF_LO(r2.x) + BF_LO(r3.x));
      acc[1] += (BF_HI(r0.x) + BF_HI(r1.x)) + (BF_HI(r2.x) + BF_HI(r3.x));
      acc[2] += (BF_LO(r0.y) + BF_LO(r1.y)) + (BF_LO(r2.y) + BF_LO(r3.y));
      acc[3] += (BF_HI(r0.y) + BF_HI(r1.y)) + (BF_HI(r2.y) + BF_HI(r3.y));
      acc[4] += (BF_LO(r0.z) + BF_LO(r1.z)) + (BF_LO(r2.z) + BF_LO(r3.z));
      acc[5] += (BF_HI(r0.z) + BF_HI(r1.z)) + (BF_HI(r2.z) + BF_HI(r3.z));
      acc[6] += (BF_LO(r0.w) + BF_LO(r1.w)) + (BF_LO(r2.w) + BF_LO(r3.w));
      acc[7] += (BF_HI(r0.w) + BF_HI(r1.w)) + (BF_HI(r2.w) + BF_HI(r3.w));
    }

    if (node < N) {
      const float di = rsqrtf((float)(cn + 1));
      const uint4 rr = *(const uint4*)(hb + (size_t)node * 64 + fq);  // self
      const float4 bq0 = *(const float4*)(bg + fq);
      const float4 bq1 = *(const float4*)(bg + fq + 4);
      float4 v0 = make_float4(
          fmaxf(di * (acc[0] + BF_LO(rr.x)) + bq0.x, 0.f),
          fmaxf(di * (acc[1] + BF_HI(rr.x)) + bq0.y, 0.f),
          fmaxf(di * (acc[2] + BF_LO(rr.y)) + bq0.z, 0.f),
          fmaxf(di * (acc[3] + BF_HI(rr.y)) + bq0.w, 0.f));
      float4 v1 = make_float4(
          fmaxf(di * (acc[4] + BF_LO(rr.z)) + bq1.x, 0.f),
          fmaxf(di * (acc[5] + BF_HI(rr.z)) + bq1.y, 0.f),
          fmaxf(di * (acc[6] + BF_LO(rr.w)) + bq1.z, 0.f),
          fmaxf(di * (acc[7] + BF_HI(rr.w)) + bq1.w, 0.f));
      *(bf8_t*)(g + (size_t)node * 64 + fq) = pack8(v0, v1);
    }
  }
}

// ---------------- MFMA MLP: 256 nodes/block, 3 layers in LDS -----------------
__global__ __launch_bounds__(256) void mlp_mfma_kernel(
    const unsigned short* __restrict__ g,
    const float* __restrict__ W1, const float* __restrict__ b1,
    const float* __restrict__ W2, const float* __restrict__ b2,
    const float* __restrict__ W3, const float* __restrict__ b3,
    float* __restrict__ out, int N) {
  __shared__ short g64[256 * 72];   // [node][feat] bf16, stride 72 (h1 aliases)
  __shared__ short h2s[256 * 40];   // [node][feat] bf16, cols 16..31 zero
  __shared__ short W1s[32 * 72];    // [n][k] k<64
  __shared__ short W2s[16 * 40];    // [n][k] k<32
  __shared__ short W3s[16 * 40];    // [n][k] k<16, rest zero
  __shared__ float b1s[32], b2s[16], b3s[16];
  short* h1s = g64;                 // [node][feat] stride 40, alias after layer1

  const int t = threadIdx.x;
  const int node0 = blockIdx.x * 256;
  for (int i = t; i < 256 * 40; i += 256) h2s[i] = 0;
  for (int i = t; i < 16 * 40; i += 256) W3s[i] = 0;
  if (t < 32) b1s[t] = b1[t];
  if (t < 16) { b2s[t] = b2[t]; b3s[t] = (t < 10) ? b3[t] : 0.f; }
  __syncthreads();
  for (int i = t; i < 2048; i += 256) { const int k = i >> 5, n = i & 31; W1s[n * 72 + k] = (short)f2bf(W1[i]); }
  for (int i = t; i < 512;  i += 256) { const int k = i >> 4, n = i & 15; W2s[n * 40 + k] = (short)f2bf(W2[i]); }
  if (t < 160) { const int k = t / 10, n = t % 10; W3s[n * 40 + k] = (short)f2bf(W3[t]); }
  // stage g: 8 lanes per row -> 1 KB contiguous per wave-instruction
  for (int i = t; i < 2048; i += 256) {
    const int row = i >> 3, q = (i & 7) << 3;
    const int nd = min(node0 + row, N - 1);
    *(uint4*)&g64[row * 72 + q] = *(const uint4*)(g + (size_t)nd * 64 + q);
  }
  __syncthreads();

  const int w = t >> 6;
  const int lane = t & 63;
  const int ml = lane & 15;
  const int quad = lane >> 4;

  // layer 1: (256x64) @ (64x32)
  bf8_t a1f[4][2], b1f[2][2];
#pragma unroll
  for (int mt = 0; mt < 4; ++mt)
#pragma unroll
    for (int ks = 0; ks < 2; ++ks)
      a1f[mt][ks] = *(const bf8_t*)&g64[(w * 64 + mt * 16 + ml) * 72 + ks * 32 + quad * 8];
#pragma unroll
  for (int nt = 0; nt < 2; ++nt)
#pragma unroll
    for (int ks = 0; ks < 2; ++ks)
      b1f[nt][ks] = *(const bf8_t*)&W1s[(nt * 16 + ml) * 72 + ks * 32 + quad * 8];
  f4_t acc1[4][2];
#pragma unroll
  for (int mt = 0; mt < 4; ++mt)
#pragma unroll
    for (int nt = 0; nt < 2; ++nt) acc1[mt][nt] = (f4_t){0.f, 0.f, 0.f, 0.f};
#pragma unroll
  for (int ks = 0; ks < 2; ++ks)
#pragma unroll
    for (int mt = 0; mt < 4; ++mt)
#pragma unroll
      for (int nt = 0; nt < 2; ++nt)
        acc1[mt][nt] = __builtin_amdgcn_mfma_f32_16x16x32_bf16(
            a1f[mt][ks], b1f[nt][ks], acc1[mt][nt], 0, 0, 0);
  __syncthreads();
#pragma unroll
  for (int mt = 0; mt < 4; ++mt)
#pragma unroll
    for (int nt = 0; nt < 2; ++nt)
#pragma unroll
      for (int reg = 0; reg < 4; ++reg) {
        const int row = w * 64 + mt * 16 + quad * 4 + reg;
        const int col = nt * 16 + ml;
        h1s[row * 40 + col] = (short)f2bf(fmaxf(acc1[mt][nt][reg] + b1s[col], 0.f));
      }
  __syncthreads();

  // layer 2: (256x32) @ (32x16)
  bf8_t a2f[4];
#pragma unroll
  for (int mt = 0; mt < 4; ++mt)
    a2f[mt] = *(const bf8_t*)&h1s[(w * 64 + mt * 16 + ml) * 40 + quad * 8];
  const bf8_t b2f = *(const bf8_t*)&W2s[ml * 40 + quad * 8];
  f4_t acc2[4];
#pragma unroll
  for (int mt = 0; mt < 4; ++mt) {
    acc2[mt] = (f4_t){0.f, 0.f, 0.f, 0.f};
    acc2[mt] = __builtin_amdgcn_mfma_f32_16x16x32_bf16(a2f[mt], b2f, acc2[mt], 0, 0, 0);
  }
  __syncthreads();
#pragma unroll
  for (int mt = 0; mt < 4; ++mt)
#pragma unroll
    for (int reg = 0; reg < 4; ++reg) {
      const int row = w * 64 + mt * 16 + quad * 4 + reg;
      h2s[row * 40 + ml] = (short)f2bf(fmaxf(acc2[mt][reg] + b2s[ml], 0.f));
    }
  __syncthreads();

  // layer 3: (256x16) @ (16x10), K zero-padded to 32
  bf8_t a3f[4];
#pragma unroll
  for (int mt = 0; mt < 4; ++mt)
    a3f[mt] = *(const bf8_t*)&h2s[(w * 64 + mt * 16 + ml) * 40 + quad * 8];
  const bf8_t b3f = *(const bf8_t*)&W3s[ml * 40 + quad * 8];
#pragma unroll
  for (int mt = 0; mt < 4; ++mt) {
    f4_t acc3 = (f4_t){0.f, 0.f, 0.f, 0.f};
    acc3 = __builtin_amdgcn_mfma_f32_16x16x32_bf16(a3f[mt], b3f, acc3, 0, 0, 0);
#pragma unroll
    for (int reg = 0; reg < 4; ++reg) {
      const int node = node0 + w * 64 + mt * 16 + quad * 4 + reg;
      if (ml < 10 && node < N) out[(size_t)node * 10 + ml] = acc3[reg] + b3s[ml];
    }
  }
}

extern "C" void kernel_launch(void* const* d_in, const int* in_sizes, int n_in,
                              void* d_out, int out_size, void* d_ws, size_t ws_size,
                              hipStream_t stream) {
  const float* x     = (const float*)d_in[0];
  const int*   ei    = (const int*)d_in[1];
  const float* W_gcn = (const float*)d_in[2];
  const float* b_gcn = (const float*)d_in[3];
  const float* W1    = (const float*)d_in[4];
  const float* b1    = (const float*)d_in[5];
  const float* W2    = (const float*)d_in[6];
  const float* b2    = (const float*)d_in[7];
  const float* W3    = (const float*)d_in[8];
  const float* b3    = (const float*)d_in[9];
  float* out = (float*)d_out;

  const int N = in_sizes[0] / F_IN;   // 100000
  const int E = in_sizes[1] / 2;      // 3200000
  const int* src = ei;
  const int* dst = ei + E;
  const int NBK = (N + 255) >> 8;     // 391 buckets of 256 nodes
  const int NCH = (E + CHUNK - 1) / CHUNK;  // 391 chunks

  unsigned short* hb = (unsigned short*)d_ws;            // (N+1)*64 us (+zero row)
  int*   deg         = (int*)(hb + (size_t)(N + 1) * 64);// N i      (0.4 MB)
  int*   espB        = deg + N;                          // E i      (12.8 MB)
  int*   segStart    = espB + E;                         // NCH*NBK i (0.61 MB)
  int*   segCnt      = segStart + NCH * NBK;             // NCH*NBK i (0.61 MB)
  unsigned short* WbT= (unsigned short*)(segCnt + NCH * NBK); // 16384 us (32 KB)
  unsigned short* g  = WbT + 16384;                      // N*64 us  (12.8 MB)

  wprep_kernel<<<64, 256, 0, stream>>>(W_gcn, WbT, hb, N);
  sort_local_kernel<<<NCH, 512, 0, stream>>>(
      src, dst, espB, segStart, segCnt, E, NBK);
  deg_hist_kernel<<<NBK, 512, 0, stream>>>(
      espB, segStart, segCnt, deg, N, NBK, NCH);

  gemm_direct_kernel<<<(N + 127) / 128, 256, 0, stream>>>(x, WbT, deg, hb, N);

  bin_agg_kernel<<<NBK, 512, 0, stream>>>(
      espB, segStart, segCnt, deg, hb, b_gcn, g, N, NBK, NCH);

  mlp_mfma_kernel<<<(N + 255) / 256, 256, 0, stream>>>(
      g, W1, b1, W2, b2, W3, b3, out, N);
}